// Round 18
// baseline (807.962 us; speedup 1.0000x reference)
//
#include <hip/hip_runtime.h>
#include <math.h>

#define T_STEPS 64
#define BATCH   512

typedef short s16x8 __attribute__((ext_vector_type(8)));
typedef float f32x4 __attribute__((ext_vector_type(4)));

#define MFMA(a,b,c) __builtin_amdgcn_mfma_f32_16x16x32_bf16((a),(b),(c),0,0,0)

__device__ __forceinline__ short f2bf(float x){
    union { float f; unsigned u; } v; v.f = x;
    unsigned r = v.u + 0x7FFFu + ((v.u >> 16) & 1u);
    return (short)(r >> 16);
}
__device__ __forceinline__ float bf2f(short s){
    union { unsigned u; float f; } v; v.u = ((unsigned)(unsigned short)s) << 16;
    return v.f;
}
__device__ __forceinline__ float frcp(float x){ return __builtin_amdgcn_rcpf(x); }
__device__ __forceinline__ float fsig(float x){ return frcp(1.f + __expf(-x)); }
__device__ __forceinline__ float ftanh(float x){ return 1.f - 2.f*frcp(1.f + __expf(2.f*x)); }
__device__ __forceinline__ float sp(float x){ return (x>20.f)? x : __logf(1.f + __expf(x)); }

// LDS-only barrier: orders LDS ops across the block; vmcnt NOT drained.
__device__ __forceinline__ void barx(){
    asm volatile("s_waitcnt lgkmcnt(0)" ::: "memory");
    __builtin_amdgcn_s_barrier();
    asm volatile("" ::: "memory");
}

// ---- packed fragment bases (fragment = 64 lanes x 8 bf16 = 1024B) ----
#define FR_GRU   0      // w_gru   K=400(13) N=600(38)  -> 494
#define FR_INP   494    // w_inp   K=36 (2)  N=200(13)  -> 26
#define FR_OBSD  520    // w_obsout[0:200]   K=200(7) N=200(13) -> 91
#define FR_OBSE  611    // w_obsout[200:]    K=1024(32) N=200(13) -> 416
#define FR_OBS   1027   // w_obs   K=200(7)  N=60(4)   -> 28
#define FR_IMG   1055   // w_imgout K=200(7) N=200(13) -> 91
#define FR_IMS   1146   // w_ims   K=200(7)  N=60(4)   -> 28
#define FR_TOT   1174

#define WS_STOCH0 1202176
#define WS_DETER0 1202304
#define WS_E      1203200

__global__ void pack_kernel(const float* w_inp, const float* w_gru, const float* w_imgout,
                            const float* w_obsout, const float* w_ims, const float* w_obs,
                            short* pk){
    int f = blockIdx.x, l = threadIdx.x;
    const float* W; int K, N, ld, KT, k0, rel;
    if      (f < FR_INP ){ W=w_gru;    K=400; N=600; ld=600; KT=13; k0=0;   rel=f; }
    else if (f < FR_OBSD){ W=w_inp;    K=36;  N=200; ld=200; KT=2;  k0=0;   rel=f-FR_INP; }
    else if (f < FR_OBSE){ W=w_obsout; K=200; N=200; ld=200; KT=7;  k0=0;   rel=f-FR_OBSD; }
    else if (f < FR_OBS ){ W=w_obsout; K=1024;N=200; ld=200; KT=32; k0=200; rel=f-FR_OBSE; }
    else if (f < FR_IMG ){ W=w_obs;    K=200; N=60;  ld=60;  KT=7;  k0=0;   rel=f-FR_OBS; }
    else if (f < FR_IMS ){ W=w_imgout; K=200; N=200; ld=200; KT=7;  k0=0;   rel=f-FR_IMG; }
    else                 { W=w_ims;    K=200; N=60;  ld=60;  KT=7;  k0=0;   rel=f-FR_IMS; }
    int nt = rel / KT, kt = rel % KT;
    int col = nt*16 + (l & 15);
    int kb  = kt*32 + (l >> 4)*8;
    s16x8 v;
    #pragma unroll
    for (int e = 0; e < 8; e++){
        int k = kb + e;
        float x = (k < K && col < N) ? W[(size_t)(k + k0)*ld + col] : 0.f;
        v[e] = f2bf(x);
    }
    *(((s16x8*)pk) + (size_t)f*64 + l) = v;
}

__global__ void init_kernel(const float* w_init, const float* w_imgout,
                            const float* ln_img_s, const float* ln_img_b,
                            const float* w_ims, const float* b_ims,
                            float* stoch0, float* deter0){
    __shared__ float d0[200], h0[200], redA[64], redB[64], mv[2];
    int t = threadIdx.x;
    if (t < 200) d0[t] = tanhf(w_init[t]);
    __syncthreads();
    if (t < 200){ float a = 0.f; for (int k = 0; k < 200; k++) a += d0[k]*w_imgout[k*200 + t]; h0[t] = a; }
    __syncthreads();
    if (t < 64){ float s = 0.f, s2 = 0.f;
        for (int j = t; j < 200; j += 64){ float v = h0[j]; s += v; s2 += v*v; }
        redA[t] = s; redB[t] = s2; }
    __syncthreads();
    if (t == 0){ float s = 0.f, s2 = 0.f;
        for (int i = 0; i < 64; i++){ s += redA[i]; s2 += redB[i]; }
        float m = s/200.f, var = s2/200.f - m*m;
        mv[0] = m; mv[1] = rsqrtf(var + 1e-3f); }
    __syncthreads();
    if (t < 200){ float v = (h0[t]-mv[0])*mv[1]*ln_img_s[t] + ln_img_b[t];
        h0[t] = v/(1.f+expf(-v)); }
    __syncthreads();
    if (t < 200) deter0[t] = d0[t];
    if (t < 30){ float a = 0.f; for (int j = 0; j < 200; j++) a += h0[j]*w_ims[j*60 + t];
        stoch0[t] = a + b_ims[t]; }
}

// E[t,b,:] = embed[t,b,:] @ w_obsout[200:1224,:]   (bf16 result)
__global__ __launch_bounds__(256) void embed_gemm(const float* embed, const short* pk, short* E){
    int tid = threadIdx.x; int w = tid >> 6, l = tid & 63;
    int row0 = blockIdx.x*128 + w*32;
    const float* A0 = embed + (size_t)(row0 + (l & 15))*1024 + (l >> 4)*8;
    const float* A1 = A0 + (size_t)16*1024;
    const s16x8* B = ((const s16x8*)pk) + (size_t)FR_OBSE*64 + l;
    f32x4 acc0[13], acc1[13];
    #pragma unroll
    for (int n = 0; n < 13; n++){ acc0[n] = (f32x4){0.f,0.f,0.f,0.f}; acc1[n] = (f32x4){0.f,0.f,0.f,0.f}; }
    for (int kt = 0; kt < 32; kt++){
        float4 x0 = *(const float4*)(A0 + kt*32), x1 = *(const float4*)(A0 + kt*32 + 4);
        float4 y0 = *(const float4*)(A1 + kt*32), y1 = *(const float4*)(A1 + kt*32 + 4);
        s16x8 af0, af1;
        af0[0]=f2bf(x0.x); af0[1]=f2bf(x0.y); af0[2]=f2bf(x0.z); af0[3]=f2bf(x0.w);
        af0[4]=f2bf(x1.x); af0[5]=f2bf(x1.y); af0[6]=f2bf(x1.z); af0[7]=f2bf(x1.w);
        af1[0]=f2bf(y0.x); af1[1]=f2bf(y0.y); af1[2]=f2bf(y0.z); af1[3]=f2bf(y0.w);
        af1[4]=f2bf(y1.x); af1[5]=f2bf(y1.y); af1[6]=f2bf(y1.z); af1[7]=f2bf(y1.w);
        #pragma unroll
        for (int n = 0; n < 13; n++){
            s16x8 bf = B[(n*32 + kt)*64];
            acc0[n] = MFMA(af0, bf, acc0[n]);
            acc1[n] = MFMA(af1, bf, acc1[n]);
        }
    }
    int rr = (l >> 4)*4, cc = l & 15;
    #pragma unroll
    for (int n = 0; n < 13; n++){
        int col = n*16 + cc;
        if (col < 200){
            #pragma unroll
            for (int r = 0; r < 4; r++){
                E[(size_t)(row0 + rr + r)*200 + col]        = f2bf(acc0[n][r]);
                E[(size_t)(row0 + 16 + rr + r)*200 + col]   = f2bf(acc1[n][r]);
            }
        }
    }
}

#define AB_STRIDE 424   // bf16; cols 0:200 x, 200:400 deter, 400:424 zero
#define XP_STRIDE 210   // f32 xpre/hpre within Uraw
#define PB_STRIDE 612   // bf16 parts within Uraw
#define QP_STRIDE 68    // f32 qpre within Uraw
#define A36_STRIDE 72   // bf16 within A36/hobuf union
#define HO_STRIDE 232   // 464B stride -> /16 odd -> conflict-free b128 reads

// 64 blocks x 8 rows: rows 8..15 of all MFMA tiles stay zero (half-empty M-tiles).
__global__ __launch_bounds__(512) void scan_kernel(
    const float* action, const float* is_first, const float* noise_post,
    const float* ln_inp_s, const float* ln_inp_b,
    const float* ln_obs_s, const float* ln_obs_b,
    const float* b_obs,
    const short* pk, const short* E, const float* stoch0g, const float* deter0g,
    float* out)
{
    __shared__ short Abuf[16*AB_STRIDE];        // 13568 B
    __shared__ __align__(16) char Uraw[19584];  // xpre/hpre f32(210) | parts bf16(612) | qpre f32(68)
    __shared__ short A36hob[16*HO_STRIDE];      // 7424 B (A36 / hobuf union)
    __shared__ float Sbuf[8*30];                // 960 B
    __shared__ short WI[26*512];                // 26624 B  w_inp fragments (step-invariant)
    __shared__ short WD[91*512];                // 93184 B  w_obsout[0:200] fragments (step-invariant)
    // total = 161344 B

    float* Uf  = (float*)Uraw;
    short* Pbs = (short*)Uraw;

    int tid = threadIdx.x;
    int w = tid >> 6, l = tid & 63;
    int row = tid >> 6;          // 8 rows, one wave per row
    int s = tid & 63;
    int r0 = blockIdx.x*8;
    const int rr = (l >> 4)*4, cc = l & 15;
    const s16x8* PK = (const s16x8*)pk;

    // ---- preload step-invariant weights into LDS (once) ----
    for (int f = w; f < 26; f += 8)
        *(s16x8*)&WI[f*512 + l*8] = PK[(size_t)(FR_INP + f)*64 + l];
    for (int f = w; f < 91; f += 8)
        *(s16x8*)&WD[f*512 + l*8] = PK[(size_t)(FR_OBSD + f)*64 + l];

    // hoisted mm4 weights (waves 0..3 only): step-invariant, 28 VGPR
    s16x8 Bm4[7];
    if (w < 4){
        #pragma unroll
        for (int kt = 0; kt < 7; kt++) Bm4[kt] = PK[(size_t)(FR_OBS + w*7 + kt)*64 + l];
    }

    float dreg[4];
    #pragma unroll
    for (int i = 0; i < 4; i++){ int j = s + 64*i; dreg[i] = (j < 200) ? deter0g[j] : 0.f; }
    if (tid < 8*30){ int rw = tid/30, j = tid%30; Sbuf[rw*30 + j] = stoch0g[j]; }

    // zero rows 8..15 of Abuf entirely + pads of rows 0..7
    for (int idx = tid; idx < 8*AB_STRIDE; idx += 512) Abuf[(8 + idx/AB_STRIDE)*AB_STRIDE + idx%AB_STRIDE] = 0;
    for (int idx = tid; idx < 8*24; idx += 512) Abuf[(idx/24)*AB_STRIDE + 400 + idx%24] = 0;
    for (int idx = tid; idx < 8*200; idx += 512) Abuf[(idx/200)*AB_STRIDE + idx%200] = 0;
    // zero A36hob shorts [576, 16*232)
    for (int idx = tid; idx < 16*HO_STRIDE - 576; idx += 512) A36hob[576 + idx] = 0;
    #pragma unroll
    for (int i = 0; i < 4; i++){ int j = s + 64*i; if (j < 200) Abuf[row*AB_STRIDE + 200 + j] = f2bf(dreg[i]); }

    // hoisted LN params (j = s + 64*i) + posterior bias
    float lisr[4], libr[4], losr[4], lobr[4];
    #pragma unroll
    for (int i = 0; i < 4; i++){ int j = s + 64*i; bool ok = j < 200;
        lisr[i] = ok ? ln_inp_s[j] : 0.f;  libr[i] = ok ? ln_inp_b[j] : 0.f;
        losr[i] = ok ? ln_obs_s[j] : 0.f;  lobr[i] = ok ? ln_obs_b[j] : 0.f;
    }
    float bo0 = 0.f, bo1 = 0.f;
    if (tid < 240){ int j = tid % 30; bo0 = b_obs[j]; bo1 = b_obs[30 + j]; }

    barx();

    for (int t = 0; t < T_STEPS; t++){
        // ---- stage 1: masking, A36 build (+re-zero rows 8-15), prefetch E + noise ----
        float f = is_first[(size_t)t*BATCH + r0 + row];
        #pragma unroll
        for (int i = 0; i < 4; i++){ int j = s + 64*i; if (j < 200){
            float d = dreg[i]*(1.f - f) + deter0g[j]*f;
            dreg[i] = d;
            Abuf[row*AB_STRIDE + 200 + j] = f2bf(d);
        }}
        {
            int j = s;  // 64 threads cover the full 64-col A36 row
            float v = 0.f;
            if (j < 30) v = Sbuf[row*30 + j]*(1.f - f) + stoch0g[j]*f;
            else if (j < 36){
                float a = action[(size_t)((size_t)t*BATCH + r0 + row)*6 + (j - 30)];
                a = a * frcp(fmaxf(fabsf(a), 1.f));
                v = a*(1.f - f);
            }
            A36hob[row*A36_STRIDE + j] = f2bf(v);
        }
        if (tid < 568) A36hob[576 + tid] = 0;   // re-zero A36 rows 8-15 (clobbered by Ho writes)
        // E prefetch: 4 scalar bf16 per thread (row layout matches stage-8's j = s+64i)
        short eA[4];
        {
            const short* Eb = E + (size_t)((size_t)t*BATCH + r0 + row)*200;
            #pragma unroll
            for (int i = 0; i < 4; i++){ int j = s + 64*i; eA[i] = (j < 200) ? Eb[j] : (short)0; }
        }
        float nz = 0.f;
        if (tid < 240){
            int rw = tid/30, j = tid%30;
            nz = noise_post[(size_t)((size_t)t*BATCH + r0 + rw)*30 + j];
        }
        barx(); // B1

        // ---- mm1: A36 @ w_inp (LDS weights) -> xpre ----
        {
            s16x8 a0 = *(s16x8*)&A36hob[(l & 15)*A36_STRIDE + (l >> 4)*8];
            s16x8 a1 = *(s16x8*)&A36hob[(l & 15)*A36_STRIDE + 32 + (l >> 4)*8];
            for (int nt = w; nt < 13; nt += 8){
                f32x4 acc = (f32x4){0.f,0.f,0.f,0.f};
                acc = MFMA(a0, *(const s16x8*)&WI[(nt*2+0)*512 + l*8], acc);
                acc = MFMA(a1, *(const s16x8*)&WI[(nt*2+1)*512 + l*8], acc);
                #pragma unroll
                for (int r = 0; r < 4; r++) Uf[(rr + r)*XP_STRIDE + nt*16 + cc] = acc[r];
            }
        }
        barx(); // B2

        // ---- stage 3: LN(inp)+silu -> Abuf[:,0:200] bf16 (one wave per row) ----
        {
            float sum = 0.f, sq = 0.f, vals[4];
            #pragma unroll
            for (int i = 0; i < 4; i++){ int j = s + 64*i;
                float v = (j < 200) ? Uf[row*XP_STRIDE + j] : 0.f;
                vals[i] = v; sum += v; sq += v*v; }
            #pragma unroll
            for (int m = 32; m >= 1; m >>= 1){ sum += __shfl_xor(sum, m); sq += __shfl_xor(sq, m); }
            float mean = sum/200.f, var = sq/200.f - mean*mean, rstd = rsqrtf(var + 1e-3f);
            #pragma unroll
            for (int i = 0; i < 4; i++){ int j = s + 64*i; if (j < 200){
                float v = (vals[i] - mean)*rstd*lisr[i] + libr[i];
                Abuf[row*AB_STRIDE + j] = f2bf(v*fsig(v));
            }}
        }
        barx(); // B3

        // ---- mm2: [x,deter] @ w_gru (streamed from L2) -> parts bf16 ----
        {
            s16x8 af[13];
            #pragma unroll
            for (int kt = 0; kt < 13; kt++)
                af[kt] = *(s16x8*)&Abuf[(l & 15)*AB_STRIDE + kt*32 + (l >> 4)*8];
            for (int nt = w; nt < 38; nt += 8){
                f32x4 acc = (f32x4){0.f,0.f,0.f,0.f};
                const s16x8* B = PK + (size_t)(FR_GRU + nt*13)*64 + l;
                #pragma unroll
                for (int kt = 0; kt < 13; kt++) acc = MFMA(af[kt], B[kt*64], acc);
                #pragma unroll
                for (int r = 0; r < 4; r++) Pbs[(rr + r)*PB_STRIDE + nt*16 + cc] = f2bf(acc[r]);
            }
        }
        barx(); // B4

        // ---- stage 5: GRU elementwise, update deter (one wave per row) ----
        {
            float* outp = out + (size_t)((size_t)t*BATCH + r0 + row)*380;
            #pragma unroll
            for (int i = 0; i < 4; i++){ int j = s + 64*i; if (j < 200){
                float rv = bf2f(Pbs[row*PB_STRIDE + j]);
                float cv = bf2f(Pbs[row*PB_STRIDE + 200 + j]);
                float uv = bf2f(Pbs[row*PB_STRIDE + 400 + j]);
                float rg = fsig(rv);
                float cg = ftanh(rg*cv);
                float ug = fsig(uv - 1.f);
                float d  = ug*cg + (1.f - ug)*dreg[i];
                dreg[i] = d;
                Abuf[row*AB_STRIDE + 200 + j] = f2bf(d);
                outp[180 + j] = d;
            }}
        }
        barx(); // B5

        // ---- mm3: deter @ w_obsout[0:200] (LDS weights) -> hpre ----
        {
            s16x8 ad[7];
            #pragma unroll
            for (int kt = 0; kt < 7; kt++)
                ad[kt] = *(s16x8*)&Abuf[(l & 15)*AB_STRIDE + 200 + kt*32 + (l >> 4)*8];
            for (int nt = w; nt < 13; nt += 8){
                f32x4 a0={0.f,0.f,0.f,0.f}, a1={0.f,0.f,0.f,0.f};
                a0 = MFMA(ad[0], *(const s16x8*)&WD[(nt*7+0)*512 + l*8], a0);
                a1 = MFMA(ad[1], *(const s16x8*)&WD[(nt*7+1)*512 + l*8], a1);
                a0 = MFMA(ad[2], *(const s16x8*)&WD[(nt*7+2)*512 + l*8], a0);
                a1 = MFMA(ad[3], *(const s16x8*)&WD[(nt*7+3)*512 + l*8], a1);
                a0 = MFMA(ad[4], *(const s16x8*)&WD[(nt*7+4)*512 + l*8], a0);
                a1 = MFMA(ad[5], *(const s16x8*)&WD[(nt*7+5)*512 + l*8], a1);
                a0 = MFMA(ad[6], *(const s16x8*)&WD[(nt*7+6)*512 + l*8], a0);
                #pragma unroll
                for (int r = 0; r < 4; r++) Uf[(rr + r)*XP_STRIDE + nt*16 + cc] = a0[r]+a1[r];
            }
        }
        barx(); // B6

        // ---- stage 8: LN(obs)+silu with inline +E -> hobuf bf16 (one wave per row) ----
        {
            float sum = 0.f, sq = 0.f, vals[4];
            #pragma unroll
            for (int i = 0; i < 4; i++){ int j = s + 64*i;
                float v = (j < 200) ? (Uf[row*XP_STRIDE + j] + bf2f(eA[i])) : 0.f;
                vals[i] = v; sum += v; sq += v*v; }
            #pragma unroll
            for (int m = 32; m >= 1; m >>= 1){ sum += __shfl_xor(sum, m); sq += __shfl_xor(sq, m); }
            float mean = sum/200.f, var = sq/200.f - mean*mean, rstd = rsqrtf(var + 1e-3f);
            #pragma unroll
            for (int i = 0; i < 4; i++){ int j = s + 64*i;
                if (j < HO_STRIDE){
                    short hv = 0;
                    if (j < 200){
                        float v = (vals[i] - mean)*rstd*losr[i] + lobr[i];
                        hv = f2bf(v*fsig(v));
                    }
                    A36hob[row*HO_STRIDE + j] = hv;
                }
            }
        }
        barx(); // B7

        // ---- mm4: ho @ w_obs -> qpre (waves 0..3, hoisted weights) ----
        if (w < 4){
            s16x8 ah[7];
            #pragma unroll
            for (int kt = 0; kt < 7; kt++)
                ah[kt] = *(s16x8*)&A36hob[(l & 15)*HO_STRIDE + kt*32 + (l >> 4)*8];
            f32x4 a0={0.f,0.f,0.f,0.f}, a1={0.f,0.f,0.f,0.f};
            a0=MFMA(ah[0],Bm4[0],a0); a1=MFMA(ah[1],Bm4[1],a1);
            a0=MFMA(ah[2],Bm4[2],a0); a1=MFMA(ah[3],Bm4[3],a1);
            a0=MFMA(ah[4],Bm4[4],a0); a1=MFMA(ah[5],Bm4[5],a1);
            a0=MFMA(ah[6],Bm4[6],a0);
            #pragma unroll
            for (int r = 0; r < 4; r++) Uf[(rr + r)*QP_STRIDE + w*16 + cc] = a0[r]+a1[r];
        }
        barx(); // B8

        // ---- stage 10: posterior stats + carry (rows 0..7) ----
        if (tid < 240){
            int rw = tid/30, j = tid%30;
            float qm = Uf[rw*QP_STRIDE + j] + bo0;
            float x  = Uf[rw*QP_STRIDE + 30 + j] + bo1;
            float qs = sp(x) + 0.1f;
            float post = qm + qs*nz;
            float* outp = out + (size_t)((size_t)t*BATCH + r0 + rw)*380;
            outp[j] = qm; outp[30 + j] = qs; outp[60 + j] = post;
            Sbuf[rw*30 + j] = post;
        }
        barx(); // B9
    }
}

// prior head for all (t,b): hp = silu(LN(deter@w_imgout)); pm,ps,prior
__global__ __launch_bounds__(64) void prior_kernel(const float* noise_prior, const float* b_ims,
                                                   const float* ln_img_s, const float* ln_img_b,
                                                   const short* pk, float* out){
    __shared__ short Ab[16*232];
    __shared__ float U[16*212];
    __shared__ short hob[16*224];
    __shared__ float qp[16*68];
    int l = threadIdx.x;
    int g0 = blockIdx.x*16;

    for (int idx = l; idx < 16*232; idx += 64){
        int rr = idx/232, c = idx%232;
        short v = 0;
        if (c < 200) v = f2bf(out[(size_t)(g0 + rr)*380 + 180 + c]);
        Ab[idx] = v;
    }
    __syncthreads();
    {
        s16x8 af[7];
        #pragma unroll
        for (int kt = 0; kt < 7; kt++)
            af[kt] = *(s16x8*)&Ab[(l & 15)*232 + kt*32 + (l >> 4)*8];
        for (int nt = 0; nt < 13; nt++){
            f32x4 acc = (f32x4){0.f,0.f,0.f,0.f};
            const s16x8* B = ((const s16x8*)pk) + (size_t)(FR_IMG + nt*7)*64 + l;
            #pragma unroll
            for (int kt = 0; kt < 7; kt++) acc = MFMA(af[kt], B[kt*64], acc);
            int rr = (l >> 4)*4, cc = l & 15;
            #pragma unroll
            for (int r = 0; r < 4; r++) U[(rr + r)*212 + nt*16 + cc] = acc[r];
        }
    }
    __syncthreads();
    {
        int rw = l >> 2, s4 = l & 3;
        float sum = 0.f, sq = 0.f, vals[50];
        #pragma unroll
        for (int i = 0; i < 50; i++){ int j = s4 + 4*i; float v = U[rw*212 + j];
            vals[i] = v; sum += v; sq += v*v; }
        sum += __shfl_xor(sum, 1); sq += __shfl_xor(sq, 1);
        sum += __shfl_xor(sum, 2); sq += __shfl_xor(sq, 2);
        float mean = sum/200.f, var = sq/200.f - mean*mean, rstd = rsqrtf(var + 1e-3f);
        #pragma unroll
        for (int i = 0; i < 50; i++){ int j = s4 + 4*i;
            float v = (vals[i] - mean)*rstd*ln_img_s[j] + ln_img_b[j];
            hob[rw*224 + j] = f2bf(v*fsig(v));
        }
    }
    for (int idx = l; idx < 16*24; idx += 64){ int rr = idx/24; hob[rr*224 + 200 + idx%24] = 0; }
    __syncthreads();
    for (int nt = 0; nt < 4; nt++){
        s16x8 af[7];
        #pragma unroll
        for (int kt = 0; kt < 7; kt++)
            af[kt] = *(s16x8*)&hob[(l & 15)*224 + kt*32 + (l >> 4)*8];
        f32x4 acc = (f32x4){0.f,0.f,0.f,0.f};
        const s16x8* B = ((const s16x8*)pk) + (size_t)(FR_IMS + nt*7)*64 + l;
        #pragma unroll
        for (int kt = 0; kt < 7; kt++) acc = MFMA(af[kt], B[kt*64], acc);
        int rr = (l >> 4)*4, cc = l & 15;
        #pragma unroll
        for (int r = 0; r < 4; r++) qp[(rr + r)*68 + nt*16 + cc] = acc[r];
    }
    __syncthreads();
    for (int idx = l; idx < 480; idx += 64){
        int rw = idx/30, j = idx%30;
        float pm = qp[rw*68 + j] + b_ims[j];
        float x  = qp[rw*68 + 30 + j] + b_ims[30 + j];
        float ps = sp(x) + 0.1f;
        float nz = noise_prior[(size_t)(g0 + rw)*30 + j];
        float prior = pm + ps*nz;
        float* op = out + (size_t)(g0 + rw)*380;
        op[90 + j] = pm; op[120 + j] = ps; op[150 + j] = prior;
    }
}

extern "C" void kernel_launch(void* const* d_in, const int* in_sizes, int n_in,
                              void* d_out, int out_size, void* d_ws, size_t ws_size,
                              hipStream_t stream){
    const float* embed    = (const float*)d_in[0];
    const float* action   = (const float*)d_in[1];
    const float* is_first = (const float*)d_in[2];
    const float* nzp      = (const float*)d_in[3];
    const float* nzq      = (const float*)d_in[4];
    const float* w_inp    = (const float*)d_in[5];
    const float* ln_inp_s = (const float*)d_in[6];
    const float* ln_inp_b = (const float*)d_in[7];
    const float* w_gru    = (const float*)d_in[8];
    const float* w_imgout = (const float*)d_in[9];
    const float* ln_img_s = (const float*)d_in[10];
    const float* ln_img_b = (const float*)d_in[11];
    const float* w_obsout = (const float*)d_in[12];
    const float* ln_obs_s = (const float*)d_in[13];
    const float* ln_obs_b = (const float*)d_in[14];
    const float* w_ims    = (const float*)d_in[15];
    const float* b_ims    = (const float*)d_in[16];
    const float* w_obs    = (const float*)d_in[17];
    const float* b_obs    = (const float*)d_in[18];
    const float* w_init   = (const float*)d_in[19];

    char*  ws    = (char*)d_ws;
    short* pk    = (short*)ws;
    float* stoch0 = (float*)(ws + WS_STOCH0);
    float* deter0 = (float*)(ws + WS_DETER0);
    short* E      = (short*)(ws + WS_E);
    float* out    = (float*)d_out;

    hipLaunchKernelGGL(pack_kernel, dim3(FR_TOT), dim3(64), 0, stream,
                       w_inp, w_gru, w_imgout, w_obsout, w_ims, w_obs, pk);
    hipLaunchKernelGGL(init_kernel, dim3(1), dim3(256), 0, stream,
                       w_init, w_imgout, ln_img_s, ln_img_b, w_ims, b_ims, stoch0, deter0);
    hipLaunchKernelGGL(embed_gemm, dim3(256), dim3(256), 0, stream, embed, pk, E);
    hipLaunchKernelGGL(scan_kernel, dim3(64), dim3(512), 0, stream,
                       action, is_first, nzq, ln_inp_s, ln_inp_b, ln_obs_s, ln_obs_b, b_obs,
                       pk, E, stoch0, deter0, out);
    hipLaunchKernelGGL(prior_kernel, dim3(2048), dim3(64), 0, stream, nzp, b_ims, ln_img_s, ln_img_b, pk, out);
}

// Round 19
// 799.194 us; speedup vs baseline: 1.0110x; 1.0110x over previous
//
#include <hip/hip_runtime.h>
#include <math.h>

#define T_STEPS 64
#define BATCH   512

typedef short s16x8 __attribute__((ext_vector_type(8)));
typedef float f32x4 __attribute__((ext_vector_type(4)));

#define MFMA(a,b,c) __builtin_amdgcn_mfma_f32_16x16x32_bf16((a),(b),(c),0,0,0)

__device__ __forceinline__ short f2bf(float x){
    union { float f; unsigned u; } v; v.f = x;
    unsigned r = v.u + 0x7FFFu + ((v.u >> 16) & 1u);
    return (short)(r >> 16);
}
__device__ __forceinline__ float bf2f(short s){
    union { unsigned u; float f; } v; v.u = ((unsigned)(unsigned short)s) << 16;
    return v.f;
}
__device__ __forceinline__ float frcp(float x){ return __builtin_amdgcn_rcpf(x); }
__device__ __forceinline__ float fsig(float x){ return frcp(1.f + __expf(-x)); }
__device__ __forceinline__ float ftanh(float x){ return 1.f - 2.f*frcp(1.f + __expf(2.f*x)); }
__device__ __forceinline__ float sp(float x){ return (x>20.f)? x : __logf(1.f + __expf(x)); }

// LDS-only barrier: orders LDS ops across the block; vmcnt NOT drained.
__device__ __forceinline__ void barx(){
    asm volatile("s_waitcnt lgkmcnt(0)" ::: "memory");
    __builtin_amdgcn_s_barrier();
    asm volatile("" ::: "memory");
}

// ---- packed fragment bases (fragment = 64 lanes x 8 bf16 = 1024B) ----
#define FR_GRU   0      // w_gru   K=400(13) N=600(38)  -> 494
#define FR_INP   494    // w_inp   K=36 (2)  N=200(13)  -> 26
#define FR_OBSD  520    // w_obsout[0:200]   K=200(7) N=200(13) -> 91
#define FR_OBSE  611    // w_obsout[200:]    K=1024(32) N=200(13) -> 416
#define FR_OBS   1027   // w_obs   K=200(7)  N=60(4)   -> 28
#define FR_IMG   1055   // w_imgout K=200(7) N=200(13) -> 91
#define FR_IMS   1146   // w_ims   K=200(7)  N=60(4)   -> 28
#define FR_TOT   1174

#define WS_STOCH0 1202176
#define WS_DETER0 1202304
#define WS_E      1203200

__global__ void pack_kernel(const float* w_inp, const float* w_gru, const float* w_imgout,
                            const float* w_obsout, const float* w_ims, const float* w_obs,
                            short* pk){
    int f = blockIdx.x, l = threadIdx.x;
    const float* W; int K, N, ld, KT, k0, rel;
    if      (f < FR_INP ){ W=w_gru;    K=400; N=600; ld=600; KT=13; k0=0;   rel=f; }
    else if (f < FR_OBSD){ W=w_inp;    K=36;  N=200; ld=200; KT=2;  k0=0;   rel=f-FR_INP; }
    else if (f < FR_OBSE){ W=w_obsout; K=200; N=200; ld=200; KT=7;  k0=0;   rel=f-FR_OBSD; }
    else if (f < FR_OBS ){ W=w_obsout; K=1024;N=200; ld=200; KT=32; k0=200; rel=f-FR_OBSE; }
    else if (f < FR_IMG ){ W=w_obs;    K=200; N=60;  ld=60;  KT=7;  k0=0;   rel=f-FR_OBS; }
    else if (f < FR_IMS ){ W=w_imgout; K=200; N=200; ld=200; KT=7;  k0=0;   rel=f-FR_IMG; }
    else                 { W=w_ims;    K=200; N=60;  ld=60;  KT=7;  k0=0;   rel=f-FR_IMS; }
    int nt = rel / KT, kt = rel % KT;
    int col = nt*16 + (l & 15);
    int kb  = kt*32 + (l >> 4)*8;
    s16x8 v;
    #pragma unroll
    for (int e = 0; e < 8; e++){
        int k = kb + e;
        float x = (k < K && col < N) ? W[(size_t)(k + k0)*ld + col] : 0.f;
        v[e] = f2bf(x);
    }
    *(((s16x8*)pk) + (size_t)f*64 + l) = v;
}

__global__ void init_kernel(const float* w_init, const float* w_imgout,
                            const float* ln_img_s, const float* ln_img_b,
                            const float* w_ims, const float* b_ims,
                            float* stoch0, float* deter0){
    __shared__ float d0[200], h0[200], redA[64], redB[64], mv[2];
    int t = threadIdx.x;
    if (t < 200) d0[t] = tanhf(w_init[t]);
    __syncthreads();
    if (t < 200){ float a = 0.f; for (int k = 0; k < 200; k++) a += d0[k]*w_imgout[k*200 + t]; h0[t] = a; }
    __syncthreads();
    if (t < 64){ float s = 0.f, s2 = 0.f;
        for (int j = t; j < 200; j += 64){ float v = h0[j]; s += v; s2 += v*v; }
        redA[t] = s; redB[t] = s2; }
    __syncthreads();
    if (t == 0){ float s = 0.f, s2 = 0.f;
        for (int i = 0; i < 64; i++){ s += redA[i]; s2 += redB[i]; }
        float m = s/200.f, var = s2/200.f - m*m;
        mv[0] = m; mv[1] = rsqrtf(var + 1e-3f); }
    __syncthreads();
    if (t < 200){ float v = (h0[t]-mv[0])*mv[1]*ln_img_s[t] + ln_img_b[t];
        h0[t] = v/(1.f+expf(-v)); }
    __syncthreads();
    if (t < 200) deter0[t] = d0[t];
    if (t < 30){ float a = 0.f; for (int j = 0; j < 200; j++) a += h0[j]*w_ims[j*60 + t];
        stoch0[t] = a + b_ims[t]; }
}

// E[t,b,:] = embed[t,b,:] @ w_obsout[200:1224,:]   (bf16 result)
__global__ __launch_bounds__(256) void embed_gemm(const float* embed, const short* pk, short* E){
    int tid = threadIdx.x; int w = tid >> 6, l = tid & 63;
    int row0 = blockIdx.x*128 + w*32;
    const float* A0 = embed + (size_t)(row0 + (l & 15))*1024 + (l >> 4)*8;
    const float* A1 = A0 + (size_t)16*1024;
    const s16x8* B = ((const s16x8*)pk) + (size_t)FR_OBSE*64 + l;
    f32x4 acc0[13], acc1[13];
    #pragma unroll
    for (int n = 0; n < 13; n++){ acc0[n] = (f32x4){0.f,0.f,0.f,0.f}; acc1[n] = (f32x4){0.f,0.f,0.f,0.f}; }
    for (int kt = 0; kt < 32; kt++){
        float4 x0 = *(const float4*)(A0 + kt*32), x1 = *(const float4*)(A0 + kt*32 + 4);
        float4 y0 = *(const float4*)(A1 + kt*32), y1 = *(const float4*)(A1 + kt*32 + 4);
        s16x8 af0, af1;
        af0[0]=f2bf(x0.x); af0[1]=f2bf(x0.y); af0[2]=f2bf(x0.z); af0[3]=f2bf(x0.w);
        af0[4]=f2bf(x1.x); af0[5]=f2bf(x1.y); af0[6]=f2bf(x1.z); af0[7]=f2bf(x1.w);
        af1[0]=f2bf(y0.x); af1[1]=f2bf(y0.y); af1[2]=f2bf(y0.z); af1[3]=f2bf(y0.w);
        af1[4]=f2bf(y1.x); af1[5]=f2bf(y1.y); af1[6]=f2bf(y1.z); af1[7]=f2bf(y1.w);
        #pragma unroll
        for (int n = 0; n < 13; n++){
            s16x8 bf = B[(n*32 + kt)*64];
            acc0[n] = MFMA(af0, bf, acc0[n]);
            acc1[n] = MFMA(af1, bf, acc1[n]);
        }
    }
    int rr = (l >> 4)*4, cc = l & 15;
    #pragma unroll
    for (int n = 0; n < 13; n++){
        int col = n*16 + cc;
        if (col < 200){
            #pragma unroll
            for (int r = 0; r < 4; r++){
                E[(size_t)(row0 + rr + r)*200 + col]        = f2bf(acc0[n][r]);
                E[(size_t)(row0 + 16 + rr + r)*200 + col]   = f2bf(acc1[n][r]);
            }
        }
    }
}

#define AB_STRIDE 424   // bf16; cols 0:200 x, 200:400 deter, 400:424 zero
#define XP_STRIDE 210   // f32 xpre/hpre within Uraw
#define PB_STRIDE 612   // bf16 parts within Uraw
#define QP_STRIDE 68    // f32 qpre within Uraw
#define A36_STRIDE 72   // bf16 within A36/hobuf union
#define HO_STRIDE 224

// 64 blocks x 8 rows: rows 8..15 of all MFMA tiles stay zero (half-empty M-tiles).
__global__ __launch_bounds__(512) void scan_kernel(
    const float* action, const float* is_first, const float* noise_post,
    const float* ln_inp_s, const float* ln_inp_b,
    const float* ln_obs_s, const float* ln_obs_b,
    const float* b_obs,
    const short* pk, const short* E, const float* stoch0g, const float* deter0g,
    float* out)
{
    __shared__ short Abuf[16*AB_STRIDE];        // 13568 B
    __shared__ __align__(16) char Uraw[19584];  // xpre/hpre f32(210) | parts bf16(612) | qpre f32(68)
    __shared__ short A36hob[16*HO_STRIDE];      // 7168 B (A36 / hobuf union)
    __shared__ float Sbuf[8*30];                // 960 B
    __shared__ short WI[26*512];                // 26624 B  w_inp fragments (step-invariant)
    __shared__ short WD[91*512];                // 93184 B  w_obsout[0:200] fragments (step-invariant)
    // total = 161088 B

    float* Uf  = (float*)Uraw;
    short* Pbs = (short*)Uraw;

    int tid = threadIdx.x;
    int w = tid >> 6, l = tid & 63;
    int row = tid >> 6;          // 8 rows, one wave per row
    int s = tid & 63;
    int r0 = blockIdx.x*8;
    const int rr = (l >> 4)*4, cc = l & 15;
    const s16x8* PK = (const s16x8*)pk;

    // ---- preload step-invariant weights into LDS (once) ----
    for (int f = w; f < 26; f += 8)
        *(s16x8*)&WI[f*512 + l*8] = PK[(size_t)(FR_INP + f)*64 + l];
    for (int f = w; f < 91; f += 8)
        *(s16x8*)&WD[f*512 + l*8] = PK[(size_t)(FR_OBSD + f)*64 + l];

    // hoisted mm4 weights (waves 0..3 only): step-invariant, 28 VGPR
    s16x8 Bm4[7];
    if (w < 4){
        #pragma unroll
        for (int kt = 0; kt < 7; kt++) Bm4[kt] = PK[(size_t)(FR_OBS + w*7 + kt)*64 + l];
    }

    float dreg[4];
    #pragma unroll
    for (int i = 0; i < 4; i++){ int j = s + 64*i; dreg[i] = (j < 200) ? deter0g[j] : 0.f; }
    if (tid < 8*30){ int rw = tid/30, j = tid%30; Sbuf[rw*30 + j] = stoch0g[j]; }

    // zero rows 8..15 of Abuf entirely + pads of rows 0..7
    for (int idx = tid; idx < 8*AB_STRIDE; idx += 512) Abuf[(8 + idx/AB_STRIDE)*AB_STRIDE + idx%AB_STRIDE] = 0;
    for (int idx = tid; idx < 8*24; idx += 512) Abuf[(idx/24)*AB_STRIDE + 400 + idx%24] = 0;
    for (int idx = tid; idx < 8*200; idx += 512) Abuf[(idx/200)*AB_STRIDE + idx%200] = 0;
    // zero A36hob shorts [576, 3584)
    for (int idx = tid; idx < 3008; idx += 512) A36hob[576 + idx] = 0;
    #pragma unroll
    for (int i = 0; i < 4; i++){ int j = s + 64*i; if (j < 200) Abuf[row*AB_STRIDE + 200 + j] = f2bf(dreg[i]); }

    // hoisted LN params (j = s + 64*i) + posterior bias
    float lisr[4], libr[4], losr[4], lobr[4];
    #pragma unroll
    for (int i = 0; i < 4; i++){ int j = s + 64*i; bool ok = j < 200;
        lisr[i] = ok ? ln_inp_s[j] : 0.f;  libr[i] = ok ? ln_inp_b[j] : 0.f;
        losr[i] = ok ? ln_obs_s[j] : 0.f;  lobr[i] = ok ? ln_obs_b[j] : 0.f;
    }
    float bo0 = 0.f, bo1 = 0.f;
    if (tid < 240){ int j = tid % 30; bo0 = b_obs[j]; bo1 = b_obs[30 + j]; }

    barx();

    for (int t = 0; t < T_STEPS; t++){
        // ---- stage 1: masking, A36 build (+re-zero rows 8-15), prefetch E + noise ----
        float f = is_first[(size_t)t*BATCH + r0 + row];
        #pragma unroll
        for (int i = 0; i < 4; i++){ int j = s + 64*i; if (j < 200){
            float d = dreg[i]*(1.f - f) + deter0g[j]*f;
            dreg[i] = d;
            Abuf[row*AB_STRIDE + 200 + j] = f2bf(d);
        }}
        {
            int j = s;  // 64 threads cover the full 64-col A36 row
            float v = 0.f;
            if (j < 30) v = Sbuf[row*30 + j]*(1.f - f) + stoch0g[j]*f;
            else if (j < 36){
                float a = action[(size_t)((size_t)t*BATCH + r0 + row)*6 + (j - 30)];
                a = a * frcp(fmaxf(fabsf(a), 1.f));
                v = a*(1.f - f);
            }
            A36hob[row*A36_STRIDE + j] = f2bf(v);
        }
        if (tid < 568) A36hob[576 + tid] = 0;   // re-zero A36 rows 8-15 (clobbered by Ho writes)
        s16x8 Ech;
        if (tid < 200){
            int er = tid/25, eq = tid%25;
            Ech = *(((const s16x8*)(E + (size_t)((size_t)t*BATCH + r0 + er)*200)) + eq);
        }
        float nz = 0.f;
        if (tid < 240){
            int rw = tid/30, j = tid%30;
            nz = noise_post[(size_t)((size_t)t*BATCH + r0 + rw)*30 + j];
        }
        barx(); // B1

        // ---- mm1: A36 @ w_inp (LDS weights) -> xpre ----
        {
            s16x8 a0 = *(s16x8*)&A36hob[(l & 15)*A36_STRIDE + (l >> 4)*8];
            s16x8 a1 = *(s16x8*)&A36hob[(l & 15)*A36_STRIDE + 32 + (l >> 4)*8];
            for (int nt = w; nt < 13; nt += 8){
                f32x4 acc = (f32x4){0.f,0.f,0.f,0.f};
                acc = MFMA(a0, *(const s16x8*)&WI[(nt*2+0)*512 + l*8], acc);
                acc = MFMA(a1, *(const s16x8*)&WI[(nt*2+1)*512 + l*8], acc);
                #pragma unroll
                for (int r = 0; r < 4; r++) Uf[(rr + r)*XP_STRIDE + nt*16 + cc] = acc[r];
            }
        }
        barx(); // B2

        // ---- stage 3: LN(inp)+silu -> Abuf[:,0:200] bf16 (one wave per row) ----
        {
            float sum = 0.f, sq = 0.f, vals[4];
            #pragma unroll
            for (int i = 0; i < 4; i++){ int j = s + 64*i;
                float v = (j < 200) ? Uf[row*XP_STRIDE + j] : 0.f;
                vals[i] = v; sum += v; sq += v*v; }
            #pragma unroll
            for (int m = 32; m >= 1; m >>= 1){ sum += __shfl_xor(sum, m); sq += __shfl_xor(sq, m); }
            float mean = sum/200.f, var = sq/200.f - mean*mean, rstd = rsqrtf(var + 1e-3f);
            #pragma unroll
            for (int i = 0; i < 4; i++){ int j = s + 64*i; if (j < 200){
                float v = (vals[i] - mean)*rstd*lisr[i] + libr[i];
                Abuf[row*AB_STRIDE + j] = f2bf(v*fsig(v));
            }}
        }
        barx(); // B3

        // ---- mm2: [x,deter] @ w_gru (streamed from L2) -> parts bf16 ----
        {
            s16x8 af[13];
            #pragma unroll
            for (int kt = 0; kt < 13; kt++)
                af[kt] = *(s16x8*)&Abuf[(l & 15)*AB_STRIDE + kt*32 + (l >> 4)*8];
            for (int nt = w; nt < 38; nt += 8){
                f32x4 acc = (f32x4){0.f,0.f,0.f,0.f};
                const s16x8* B = PK + (size_t)(FR_GRU + nt*13)*64 + l;
                #pragma unroll
                for (int kt = 0; kt < 13; kt++) acc = MFMA(af[kt], B[kt*64], acc);
                #pragma unroll
                for (int r = 0; r < 4; r++) Pbs[(rr + r)*PB_STRIDE + nt*16 + cc] = f2bf(acc[r]);
            }
        }
        barx(); // B4

        // ---- stage 5: GRU elementwise, update deter (one wave per row) ----
        {
            float* outp = out + (size_t)((size_t)t*BATCH + r0 + row)*380;
            #pragma unroll
            for (int i = 0; i < 4; i++){ int j = s + 64*i; if (j < 200){
                float rv = bf2f(Pbs[row*PB_STRIDE + j]);
                float cv = bf2f(Pbs[row*PB_STRIDE + 200 + j]);
                float uv = bf2f(Pbs[row*PB_STRIDE + 400 + j]);
                float rg = fsig(rv);
                float cg = ftanh(rg*cv);
                float ug = fsig(uv - 1.f);
                float d  = ug*cg + (1.f - ug)*dreg[i];
                dreg[i] = d;
                Abuf[row*AB_STRIDE + 200 + j] = f2bf(d);
                outp[180 + j] = d;
            }}
        }
        barx(); // B5

        // ---- mm3: deter @ w_obsout[0:200] (LDS weights) -> hpre ----
        {
            s16x8 ad[7];
            #pragma unroll
            for (int kt = 0; kt < 7; kt++)
                ad[kt] = *(s16x8*)&Abuf[(l & 15)*AB_STRIDE + 200 + kt*32 + (l >> 4)*8];
            for (int nt = w; nt < 13; nt += 8){
                f32x4 a0={0.f,0.f,0.f,0.f}, a1={0.f,0.f,0.f,0.f};
                a0 = MFMA(ad[0], *(const s16x8*)&WD[(nt*7+0)*512 + l*8], a0);
                a1 = MFMA(ad[1], *(const s16x8*)&WD[(nt*7+1)*512 + l*8], a1);
                a0 = MFMA(ad[2], *(const s16x8*)&WD[(nt*7+2)*512 + l*8], a0);
                a1 = MFMA(ad[3], *(const s16x8*)&WD[(nt*7+3)*512 + l*8], a1);
                a0 = MFMA(ad[4], *(const s16x8*)&WD[(nt*7+4)*512 + l*8], a0);
                a1 = MFMA(ad[5], *(const s16x8*)&WD[(nt*7+5)*512 + l*8], a1);
                a0 = MFMA(ad[6], *(const s16x8*)&WD[(nt*7+6)*512 + l*8], a0);
                #pragma unroll
                for (int r = 0; r < 4; r++) Uf[(rr + r)*XP_STRIDE + nt*16 + cc] = a0[r]+a1[r];
            }
        }
        barx(); // B6

        // ---- stage 7: += E (rows 0..7) ----
        if (tid < 200){
            int er = tid/25, eq = tid%25;
            #pragma unroll
            for (int e = 0; e < 8; e++) Uf[er*XP_STRIDE + eq*8 + e] += bf2f(Ech[e]);
        }
        barx(); // B7

        // ---- stage 8: LN(obs)+silu -> hobuf bf16 (one wave per row; zeroes pads 200:224) ----
        {
            float sum = 0.f, sq = 0.f, vals[4];
            #pragma unroll
            for (int i = 0; i < 4; i++){ int j = s + 64*i;
                float v = (j < 200) ? Uf[row*XP_STRIDE + j] : 0.f;
                vals[i] = v; sum += v; sq += v*v; }
            #pragma unroll
            for (int m = 32; m >= 1; m >>= 1){ sum += __shfl_xor(sum, m); sq += __shfl_xor(sq, m); }
            float mean = sum/200.f, var = sq/200.f - mean*mean, rstd = rsqrtf(var + 1e-3f);
            #pragma unroll
            for (int i = 0; i < 4; i++){ int j = s + 64*i;
                if (j < 224){
                    short hv = 0;
                    if (j < 200){
                        float v = (vals[i] - mean)*rstd*losr[i] + lobr[i];
                        hv = f2bf(v*fsig(v));
                    }
                    A36hob[row*HO_STRIDE + j] = hv;
                }
            }
        }
        barx(); // B8

        // ---- mm4: ho @ w_obs -> qpre (waves 0..3, hoisted weights) ----
        if (w < 4){
            s16x8 ah[7];
            #pragma unroll
            for (int kt = 0; kt < 7; kt++)
                ah[kt] = *(s16x8*)&A36hob[(l & 15)*HO_STRIDE + kt*32 + (l >> 4)*8];
            f32x4 a0={0.f,0.f,0.f,0.f}, a1={0.f,0.f,0.f,0.f};
            a0=MFMA(ah[0],Bm4[0],a0); a1=MFMA(ah[1],Bm4[1],a1);
            a0=MFMA(ah[2],Bm4[2],a0); a1=MFMA(ah[3],Bm4[3],a1);
            a0=MFMA(ah[4],Bm4[4],a0); a1=MFMA(ah[5],Bm4[5],a1);
            a0=MFMA(ah[6],Bm4[6],a0);
            #pragma unroll
            for (int r = 0; r < 4; r++) Uf[(rr + r)*QP_STRIDE + w*16 + cc] = a0[r]+a1[r];
        }
        barx(); // B9

        // ---- stage 10: posterior stats + carry (rows 0..7) ----
        if (tid < 240){
            int rw = tid/30, j = tid%30;
            float qm = Uf[rw*QP_STRIDE + j] + bo0;
            float x  = Uf[rw*QP_STRIDE + 30 + j] + bo1;
            float qs = sp(x) + 0.1f;
            float post = qm + qs*nz;
            float* outp = out + (size_t)((size_t)t*BATCH + r0 + rw)*380;
            outp[j] = qm; outp[30 + j] = qs; outp[60 + j] = post;
            Sbuf[rw*30 + j] = post;
        }
        barx(); // B10
    }
}

// prior head for all (t,b): hp = silu(LN(deter@w_imgout)); pm,ps,prior
__global__ __launch_bounds__(64) void prior_kernel(const float* noise_prior, const float* b_ims,
                                                   const float* ln_img_s, const float* ln_img_b,
                                                   const short* pk, float* out){
    __shared__ short Ab[16*232];
    __shared__ float U[16*212];
    __shared__ short hob[16*224];
    __shared__ float qp[16*68];
    int l = threadIdx.x;
    int g0 = blockIdx.x*16;

    for (int idx = l; idx < 16*232; idx += 64){
        int rr = idx/232, c = idx%232;
        short v = 0;
        if (c < 200) v = f2bf(out[(size_t)(g0 + rr)*380 + 180 + c]);
        Ab[idx] = v;
    }
    __syncthreads();
    {
        s16x8 af[7];
        #pragma unroll
        for (int kt = 0; kt < 7; kt++)
            af[kt] = *(s16x8*)&Ab[(l & 15)*232 + kt*32 + (l >> 4)*8];
        for (int nt = 0; nt < 13; nt++){
            f32x4 acc = (f32x4){0.f,0.f,0.f,0.f};
            const s16x8* B = ((const s16x8*)pk) + (size_t)(FR_IMG + nt*7)*64 + l;
            #pragma unroll
            for (int kt = 0; kt < 7; kt++) acc = MFMA(af[kt], B[kt*64], acc);
            int rr = (l >> 4)*4, cc = l & 15;
            #pragma unroll
            for (int r = 0; r < 4; r++) U[(rr + r)*212 + nt*16 + cc] = acc[r];
        }
    }
    __syncthreads();
    {
        int rw = l >> 2, s4 = l & 3;
        float sum = 0.f, sq = 0.f, vals[50];
        #pragma unroll
        for (int i = 0; i < 50; i++){ int j = s4 + 4*i; float v = U[rw*212 + j];
            vals[i] = v; sum += v; sq += v*v; }
        sum += __shfl_xor(sum, 1); sq += __shfl_xor(sq, 1);
        sum += __shfl_xor(sum, 2); sq += __shfl_xor(sq, 2);
        float mean = sum/200.f, var = sq/200.f - mean*mean, rstd = rsqrtf(var + 1e-3f);
        #pragma unroll
        for (int i = 0; i < 50; i++){ int j = s4 + 4*i;
            float v = (vals[i] - mean)*rstd*ln_img_s[j] + ln_img_b[j];
            hob[rw*224 + j] = f2bf(v*fsig(v));
        }
    }
    for (int idx = l; idx < 16*24; idx += 64){ int rr = idx/24; hob[rr*224 + 200 + idx%24] = 0; }
    __syncthreads();
    for (int nt = 0; nt < 4; nt++){
        s16x8 af[7];
        #pragma unroll
        for (int kt = 0; kt < 7; kt++)
            af[kt] = *(s16x8*)&hob[(l & 15)*224 + kt*32 + (l >> 4)*8];
        f32x4 acc = (f32x4){0.f,0.f,0.f,0.f};
        const s16x8* B = ((const s16x8*)pk) + (size_t)(FR_IMS + nt*7)*64 + l;
        #pragma unroll
        for (int kt = 0; kt < 7; kt++) acc = MFMA(af[kt], B[kt*64], acc);
        int rr = (l >> 4)*4, cc = l & 15;
        #pragma unroll
        for (int r = 0; r < 4; r++) qp[(rr + r)*68 + nt*16 + cc] = acc[r];
    }
    __syncthreads();
    for (int idx = l; idx < 480; idx += 64){
        int rw = idx/30, j = idx%30;
        float pm = qp[rw*68 + j] + b_ims[j];
        float x  = qp[rw*68 + 30 + j] + b_ims[30 + j];
        float ps = sp(x) + 0.1f;
        float nz = noise_prior[(size_t)(g0 + rw)*30 + j];
        float prior = pm + ps*nz;
        float* op = out + (size_t)(g0 + rw)*380;
        op[90 + j] = pm; op[120 + j] = ps; op[150 + j] = prior;
    }
}

extern "C" void kernel_launch(void* const* d_in, const int* in_sizes, int n_in,
                              void* d_out, int out_size, void* d_ws, size_t ws_size,
                              hipStream_t stream){
    const float* embed    = (const float*)d_in[0];
    const float* action   = (const float*)d_in[1];
    const float* is_first = (const float*)d_in[2];
    const float* nzp      = (const float*)d_in[3];
    const float* nzq      = (const float*)d_in[4];
    const float* w_inp    = (const float*)d_in[5];
    const float* ln_inp_s = (const float*)d_in[6];
    const float* ln_inp_b = (const float*)d_in[7];
    const float* w_gru    = (const float*)d_in[8];
    const float* w_imgout = (const float*)d_in[9];
    const float* ln_img_s = (const float*)d_in[10];
    const float* ln_img_b = (const float*)d_in[11];
    const float* w_obsout = (const float*)d_in[12];
    const float* ln_obs_s = (const float*)d_in[13];
    const float* ln_obs_b = (const float*)d_in[14];
    const float* w_ims    = (const float*)d_in[15];
    const float* b_ims    = (const float*)d_in[16];
    const float* w_obs    = (const float*)d_in[17];
    const float* b_obs    = (const float*)d_in[18];
    const float* w_init   = (const float*)d_in[19];

    char*  ws    = (char*)d_ws;
    short* pk    = (short*)ws;
    float* stoch0 = (float*)(ws + WS_STOCH0);
    float* deter0 = (float*)(ws + WS_DETER0);
    short* E      = (short*)(ws + WS_E);
    float* out    = (float*)d_out;

    hipLaunchKernelGGL(pack_kernel, dim3(FR_TOT), dim3(64), 0, stream,
                       w_inp, w_gru, w_imgout, w_obsout, w_ims, w_obs, pk);
    hipLaunchKernelGGL(init_kernel, dim3(1), dim3(256), 0, stream,
                       w_init, w_imgout, ln_img_s, ln_img_b, w_ims, b_ims, stoch0, deter0);
    hipLaunchKernelGGL(embed_gemm, dim3(256), dim3(256), 0, stream, embed, pk, E);
    hipLaunchKernelGGL(scan_kernel, dim3(64), dim3(512), 0, stream,
                       action, is_first, nzq, ln_inp_s, ln_inp_b, ln_obs_s, ln_obs_b, b_obs,
                       pk, E, stoch0, deter0, out);
    hipLaunchKernelGGL(prior_kernel, dim3(2048), dim3(64), 0, stream, nzp, b_ims, ln_img_s, ln_img_b, pk, out);
}